// Round 1
// 263.944 us; speedup vs baseline: 1.1087x; 1.1087x over previous
//
#include <hip/hip_runtime.h>

#define MDIM 8192
#define NDIM 8192
#define KDIM 64

typedef __attribute__((ext_vector_type(8))) short bf16x8;
typedef __attribute__((ext_vector_type(4))) float f32x4;

// LDS row stride in ushorts: 64 payload + 8 pad => 144 B rows.
// 144 % 16 == 0 keeps ds_read_b128 16B-aligned; 144B = 36 banks breaks the
// power-of-2 row->bank aliasing (residual 2-way conflicts are free on gfx950).
#define LDS_STRIDE 72

__device__ __forceinline__ unsigned short f32_to_bf16(float f) {
    union { float f; unsigned int u; } v;
    v.f = f;
    unsigned int u = v.u;
    u += 0x7FFFu + ((u >> 16) & 1u);  // round-to-nearest-even
    return (unsigned short)(u >> 16);
}

__global__ __launch_bounds__(256, 3)
void tmatmul_kernel(const float* __restrict__ A, const float* __restrict__ B,
                    float* __restrict__ C) {
    // Single shared block so we can re-use it as the C-epilogue bounce buffer.
    // Layout: sA = smem[0 .. 128*72), sB = smem[128*72 .. 2*128*72)  (bf16 bits)
    // After the MFMA loop (post-barrier) the same 36,864 B are reinterpreted as
    // per-wave float slabs: wave wv owns floats [wv*2048, wv*2048+2048) = 8 KB
    // (two ping-pong 4 KB buffers), total 32 KB <= 36,864 B.
    __shared__ __align__(16) unsigned short smem[2 * 128 * LDS_STRIDE];
    unsigned short* sA = smem;                       // sA[m][k]
    unsigned short* sB = smem + 128 * LDS_STRIDE;    // sB[n][k] (B transposed)

    const int tid = threadIdx.x;
    const int m0 = blockIdx.y << 7;
    const int n0 = blockIdx.x << 7;

    // ---- Stage A tile: 128 x 64 fp32 -> bf16, row-major. float4 coalesced. ----
    {
        const int row_base = tid >> 4;         // 0..15
        const int col = (tid & 15) << 2;       // 0,4,...,60
#pragma unroll
        for (int i = 0; i < 8; ++i) {
            const int row = row_base + (i << 4);
            const float4 v =
                *reinterpret_cast<const float4*>(&A[(size_t)(m0 + row) * KDIM + col]);
            ushort4 h;
            h.x = f32_to_bf16(v.x);
            h.y = f32_to_bf16(v.y);
            h.z = f32_to_bf16(v.z);
            h.w = f32_to_bf16(v.w);
            *reinterpret_cast<ushort4*>(&sA[row * LDS_STRIDE + col]) = h;
        }
    }

    // ---- Stage B tile: 64 x 128 fp32, transposed into sB[n][k] as bf16. ----
    // Each thread reads 4 k-values at a fixed n (each read coalesced across
    // lanes along n), writes one 8B chunk along k -> vector LDS write.
    {
#pragma unroll
        for (int i = 0; i < 8; ++i) {
            const int n = (tid & 63) + ((i & 1) << 6);           // 0..127
            const int k0 = ((tid >> 6) << 2) + ((i >> 1) << 4);  // 0,4,...,60
            const size_t gb = (size_t)k0 * NDIM + n0 + n;
            const float b0 = B[gb];
            const float b1 = B[gb + NDIM];
            const float b2 = B[gb + 2 * NDIM];
            const float b3 = B[gb + 3 * NDIM];
            ushort4 h;
            h.x = f32_to_bf16(b0);
            h.y = f32_to_bf16(b1);
            h.z = f32_to_bf16(b2);
            h.w = f32_to_bf16(b3);
            *reinterpret_cast<ushort4*>(&sB[n * LDS_STRIDE + k0]) = h;
        }
    }

    __syncthreads();

    // ---- Compute: 4 waves in 2x2, each wave a 64x64 strip (4x4 MFMA tiles, K=64=2 steps) ----
    const int lane = tid & 63;
    const int wv = tid >> 6;
    const int wm = (wv >> 1) << 6;  // 0 or 64
    const int wn = (wv & 1) << 6;   // 0 or 64
    const int l15 = lane & 15;
    const int quad = lane >> 4;

    bf16x8 afrag[4][2];
#pragma unroll
    for (int mt = 0; mt < 4; ++mt)
#pragma unroll
        for (int ks = 0; ks < 2; ++ks)
            afrag[mt][ks] = *reinterpret_cast<const bf16x8*>(
                &sA[(wm + mt * 16 + l15) * LDS_STRIDE + ks * 32 + quad * 8]);

    f32x4 acc[4][4];
    const f32x4 zero = {0.0f, 0.0f, 0.0f, 0.0f};
#pragma unroll
    for (int mt = 0; mt < 4; ++mt)
#pragma unroll
        for (int nt = 0; nt < 4; ++nt)
            acc[mt][nt] = zero;

    // Operand swap: D = (B^T-frag) x (A^T-frag) = C^T tile. Lane then holds
    // C[m = l15][n = quad*4 + reg] -> 4 consecutive columns -> float4 chunks.
#pragma unroll
    for (int nt = 0; nt < 4; ++nt) {
        const bf16x8 bf0 = *reinterpret_cast<const bf16x8*>(
            &sB[(wn + nt * 16 + l15) * LDS_STRIDE + quad * 8]);
        const bf16x8 bf1 = *reinterpret_cast<const bf16x8*>(
            &sB[(wn + nt * 16 + l15) * LDS_STRIDE + 32 + quad * 8]);
#pragma unroll
        for (int mt = 0; mt < 4; ++mt) {
            acc[mt][nt] = __builtin_amdgcn_mfma_f32_16x16x32_bf16(
                bf0, afrag[mt][0], acc[mt][nt], 0, 0, 0);
            acc[mt][nt] = __builtin_amdgcn_mfma_f32_16x16x32_bf16(
                bf1, afrag[mt][1], acc[mt][nt], 0, 0, 0);
        }
    }

    // All waves must be done reading sA/sB before we recycle the LDS as the
    // C bounce buffer.
    __syncthreads();

    // ---- Epilogue: per-wave swizzled LDS bounce -> fully contiguous stores. ----
    // Fragment layout gives lane (l15, quad) the floats C[l15][nt*16+quad*4 .. +3]
    // of its wave's 64x64 quadrant: a store directly from acc emits 16 scattered
    // 64 B segments per instruction (half cache lines). Instead each wave writes
    // one 16x64 (mt) slice into its private 4 KB LDS slab with an XOR granule
    // swizzle (granule g at row r stored at g^r -> uniform 8 words/bank, i.e.
    // conflict-free for b128), re-reads it row-major, and stores 4 rows x 256 B
    // contiguous per global_store_dwordx4 (1 KiB/instruction, full 128 B lines).
    float* cw = reinterpret_cast<float*>(smem) + (wv << 11);  // 8 KB per wave
#pragma unroll
    for (int mt = 0; mt < 4; ++mt) {
        float* buf = cw + ((mt & 1) << 10);  // ping-pong 4 KB halves
        // Scatter this mt-slice into LDS (row = l15, granule g = nt*4+quad).
#pragma unroll
        for (int nt = 0; nt < 4; ++nt) {
            const int g = (nt << 2) + quad;
            *reinterpret_cast<f32x4*>(&buf[(l15 << 6) + ((g ^ l15) << 2)]) =
                acc[mt][nt];
        }
        // Gather row-major: instruction j covers rows j*4+quad, granule = l15.
        const int m_base = m0 + wm + (mt << 4);
        const int n_base = n0 + wn + (l15 << 2);
#pragma unroll
        for (int j = 0; j < 4; ++j) {
            const int rr = (j << 2) + quad;
            const f32x4 v = *reinterpret_cast<const f32x4*>(
                &buf[(rr << 6) + ((l15 ^ rr) << 2)]);
            __builtin_nontemporal_store(
                v, reinterpret_cast<f32x4*>(&C[(size_t)(m_base + rr) * NDIM + n_base]));
        }
    }
}

extern "C" void kernel_launch(void* const* d_in, const int* in_sizes, int n_in,
                              void* d_out, int out_size, void* d_ws, size_t ws_size,
                              hipStream_t stream) {
    const float* A = (const float*)d_in[0];
    const float* B = (const float*)d_in[1];
    float* C = (float*)d_out;
    dim3 grid(NDIM / 128, MDIM / 128);
    tmatmul_kernel<<<grid, dim3(256, 1, 1), 0, stream>>>(A, B, C);
}